// Round 13
// baseline (824.630 us; speedup 1.0000x reference)
//
#include <hip/hip_runtime.h>
#include <math.h>

// Problem constants: B=2, C=256, DM=512, H=8, D=64, SPARSE_K=64
typedef __bf16 bf16;
typedef __attribute__((ext_vector_type(4))) __bf16 bf16x4;
typedef __attribute__((ext_vector_type(8))) __bf16 bf16x8;
typedef __attribute__((ext_vector_type(4))) float floatx4;

#define NE   262144        // 512*512
#define NBLK 1024          // persistent grid: 4 blocks/CU x 256 CUs

#define MFMA16(A_, B_, C_) __builtin_amdgcn_mfma_f32_16x16x32_bf16(A_, B_, C_, 0, 0, 0)

struct MegaArgs {
    const float *x, *Wq, *bq, *Wk, *bk, *Wv, *bv;
    const float *w1, *b1, *w2, *b2, *Wo, *bo;
    float* out;
    float *qb, *vb;
    bf16 *khi, *kmid, *klo;
    bf16 *xs, *wqs, *wks, *wvs;   // split triple bases (+NE, +2NE)
    int* bar;                     // 2 barrier counters, memset to 0 pre-launch
};

// ---------------------------------------------------------------------------
__device__ __forceinline__ float gelu_exact(float x) {
    float tt = x * 0.70710678118654752440f;
    float e;
    if (__builtin_expect(fabsf(tt) > 0.5f, 0)) {
        e = erff(tt);
    } else {
        float s = tt * tt;
        e = tt * fmaf(s, fmaf(s, fmaf(s, fmaf(s, fmaf(s,
                -8.548327023450852e-4f, 5.223977625442188e-3f),
                -2.6866170645131252e-2f), 0.11283791670955126f),
                -0.3761263890318375f), 1.1283791670955126f);
    }
    return 0.5f * x * (1.0f + e);
}

__device__ __forceinline__ void split3(float a, bf16& h, bf16& m, bf16& l) {
    h = (bf16)a;  float r1 = a - (float)h;
    m = (bf16)r1; float r2 = r1 - (float)m;
    l = (bf16)r2;
}

// ---------------------------------------------------------------------------
// Device-scope one-shot grid barrier. All NBLK blocks are co-resident
// (launch_bounds(256,4): VGPR<=128, LDS 15.5K -> >=4 blocks/CU guaranteed).
// __threadfence (seq_cst agent fence) before = release flush; after = acquire
// invalidate, so post-barrier loads see pre-barrier remote writes (cross-XCD).
// ---------------------------------------------------------------------------
__device__ __forceinline__ void grid_barrier(int* cnt) {
    __threadfence();
    __syncthreads();
    if (threadIdx.x == 0) {
        __hip_atomic_fetch_add(cnt, 1, __ATOMIC_ACQ_REL, __HIP_MEMORY_SCOPE_AGENT);
        while (__hip_atomic_load(cnt, __ATOMIC_ACQUIRE, __HIP_MEMORY_SCOPE_AGENT) < NBLK)
            __builtin_amdgcn_s_sleep(2);
    }
    __syncthreads();
    __threadfence();
}

// ---------------------------------------------------------------------------
// Phase A: split x,Wq,Wk,Wv into frag-major bf16 triples (1 unit per block),
// and init out = bo (1 element per thread; required before phase C atomics).
// ---------------------------------------------------------------------------
__device__ __forceinline__ void phase_split_init(const MegaArgs& P) {
    const int bid = blockIdx.x, tid = threadIdx.x;
    int gid = bid * 256 + tid;                 // 262144 = B*C*DM exactly
    P.out[gid] = P.bo[gid & 511];

    const float* srcs[4] = {P.x, P.Wq, P.Wk, P.Wv};
    bf16* dsts[4] = {P.xs, P.wqs, P.wks, P.wvs};
    int z = bid >> 8, bx = bid & 255;
    const float* src = srcs[z];
    bf16* dh = dsts[z]; bf16* dm = dh + NE; bf16* dl = dh + 2 * NE;
    int t = bx * 256 + tid;
    int row = t >> 7, kq = (t & 127) * 4;
    int rt = row >> 4, rm = row & 15;
    int ks = kq >> 5, q4 = (kq >> 3) & 3, u0 = kq & 7;
    int dst = ((rt * 16 + ks) * 64 + q4 * 16 + rm) * 8 + u0;
    float4 vv = *(const float4*)&src[row * 512 + kq];
    float a4[4] = {vv.x, vv.y, vv.z, vv.w};
    bf16x4 h, m, l;
    #pragma unroll
    for (int u = 0; u < 4; u++) {
        bf16 hh, mm, ll;
        split3(a4[u], hh, mm, ll);
        h[u] = hh; m[u] = mm; l[u] = ll;
    }
    *(bf16x4*)&dh[dst] = h;
    *(bf16x4*)&dm[dst] = m;
    *(bf16x4*)&dl[dst] = l;
}

// ---------------------------------------------------------------------------
// Phase B: QKV projections, triple-split MFMA, one 16x16 tile per WAVE
// (R11-validated). gw in [0,3072): z = gw>>10 (Q,K,V), mt/bx from remainder.
// Q,V -> heads fp32; K -> frag-major split triple directly.
// ---------------------------------------------------------------------------
__device__ __forceinline__ void phase_mm_qkv(const MegaArgs& P, int gw) {
    const int lane = threadIdx.x & 63;
    const int m16 = lane & 15, q4 = lane >> 4;
    int z = gw >> 10;
    int rem = gw & 1023;
    int mt = rem >> 5, bx = rem & 31;
    const bf16* Wb; const float* bias; float* outf; int mode;
    if (z == 0)      { Wb = P.wqs; bias = P.bq; outf = P.qb; mode = 1; }
    else if (z == 1) { Wb = P.wks; bias = P.bk; outf = nullptr; mode = 2; }
    else             { Wb = P.wvs; bias = P.bv; outf = P.vb; mode = 1; }
    const bf16 *Ah = P.xs, *Am = P.xs + NE, *Al = P.xs + 2 * NE;
    const bf16 *Wh = Wb,   *Wm = Wb + NE,   *Wl = Wb + 2 * NE;

    floatx4 acc;
    {
        float bv = bias[bx * 16 + m16];
        acc[0] = bv; acc[1] = bv; acc[2] = bv; acc[3] = bv;
    }
    #pragma unroll 4
    for (int ks = 0; ks < 16; ks++) {
        int sa = ((mt * 16 + ks) * 64 + lane) * 8;
        bf16x8 ah = *(const bf16x8*)&Ah[sa];
        bf16x8 am = *(const bf16x8*)&Am[sa];
        bf16x8 al = *(const bf16x8*)&Al[sa];
        int sw = ((bx * 16 + ks) * 64 + lane) * 8;
        bf16x8 wh = *(const bf16x8*)&Wh[sw];
        bf16x8 wm = *(const bf16x8*)&Wm[sw];
        bf16x8 wl = *(const bf16x8*)&Wl[sw];
        acc = MFMA16(ah, wh, acc);
        acc = MFMA16(ah, wm, acc);
        acc = MFMA16(am, wh, acc);
        acc = MFMA16(ah, wl, acc);
        acc = MFMA16(al, wh, acc);
        acc = MFMA16(am, wm, acc);
    }
    const int n = bx * 16 + m16;
    #pragma unroll
    for (int r = 0; r < 4; r++) {
        int m = mt * 16 + q4 * 4 + r;
        float val = acc[r];
        if (mode == 1) {
            outf[(((m >> 8) * 8 + (n >> 6)) * 256 + (m & 255)) * 64 + (n & 63)] = val;
        } else {
            int krow = ((m >> 8) * 8 + (n >> 6)) * 256 + (m & 255);
            int d = n & 63;
            int dst = (((krow >> 4) * 2 + (d >> 5)) * 64 + ((d >> 3) & 3) * 16 + (krow & 15)) * 8 + (d & 7);
            bf16 h, mm, l;
            split3(val, h, mm, l);
            P.khi[dst] = h; P.kmid[dst] = mm; P.klo[dst] = l;
        }
    }
}

// ---------------------------------------------------------------------------
// Phase C: fused second-order scores (triple-split MFMA, K-level-ordered for
// register relief) + top-64 bitonic + softmax + attn@V + INTEGRATED output
// projection (per-head fp32 dots + device atomicAdd into out; out pre-init
// to bo in phase A). One (bh, i-pair) unit; each block runs exactly 2 units.
// ---------------------------------------------------------------------------
__device__ __forceinline__ void phase_fused(const MegaArgs& P, int unit) {
    const int i2 = unit & 127;
    const int bh = unit >> 7;
    const int t  = threadIdx.x;
    const int lane = t & 63, w = t >> 6;
    const int m16 = lane & 15, q4 = lane >> 4;

    __shared__ float part[2][4][256];
    __shared__ float sc[2][256];
    __shared__ float qpb_s[2][64];
    __shared__ float sbuf[2][256];
    __shared__ float red[2][4][64];
    __shared__ float red2[2][4];
    __shared__ float thr_s[2], smax_s[2];
    __shared__ float oarr[2][64];

    const int f = w * 16 + m16;
    const float* w1row = P.w1 + f * 192;

    // ---- build A_i fragments in registers + qpb
    bf16x8 Ah[2][2], Am[2][2], Al[2][2];
    #pragma unroll
    for (int i01 = 0; i01 < 2; i01++) {
        const float* qrow = P.qb + (bh * 256 + i2 * 2 + i01) * 64;
        float qa = 0.f;
        #pragma unroll
        for (int ks = 0; ks < 2; ks++) {
            int e0 = ks * 32 + q4 * 8;
            #pragma unroll
            for (int u = 0; u < 2; u++) {
                int e = e0 + u * 4;
                float4 wa = *(const float4*)&w1row[e];
                float4 wb = *(const float4*)&w1row[64 + e];
                float4 wc = *(const float4*)&w1row[128 + e];
                float4 qv = *(const float4*)&qrow[e];
                qa += wa.x * qv.x + wa.y * qv.y + wa.z * qv.z + wa.w * qv.w;
                float av[4];
                av[0] = fmaf(wc.x, qv.x, wb.x);
                av[1] = fmaf(wc.y, qv.y, wb.y);
                av[2] = fmaf(wc.z, qv.z, wb.z);
                av[3] = fmaf(wc.w, qv.w, wb.w);
                #pragma unroll
                for (int uu = 0; uu < 4; uu++) {
                    bf16 h, m, l;
                    split3(av[uu], h, m, l);
                    Ah[i01][ks][u * 4 + uu] = h;
                    Am[i01][ks][u * 4 + uu] = m;
                    Al[i01][ks][u * 4 + uu] = l;
                }
            }
        }
        qa += __shfl_xor(qa, 16);
        qa += __shfl_xor(qa, 32);
        if (lane < 16) qpb_s[i01][w * 16 + lane] = qa + P.b1[w * 16 + lane];
    }
    __syncthreads();

    floatx4 qpbr[2];
    qpbr[0] = *(const floatx4*)&qpb_s[0][w * 16 + q4 * 4];
    qpbr[1] = *(const floatx4*)&qpb_s[1][w * 16 + q4 * 4];
    const float4 w2f = *(const float4*)&P.w2[w * 16 + q4 * 4];
    const float b2v = P.b2[0];

    // ---- main loop over j-tiles (K-level-ordered MFMAs: Kh -> Km -> Kl)
    #pragma unroll 2
    for (int jt = 0; jt < 16; jt++) {
        int kb = ((bh * 16 + jt) * 2 * 64 + lane) * 8;
        floatx4 a0 = qpbr[0], a1 = qpbr[1];
        bf16x8 Kh0 = *(const bf16x8*)&P.khi [kb];
        bf16x8 Kh1 = *(const bf16x8*)&P.khi [kb + 512];
        a0 = MFMA16(Ah[0][0], Kh0, a0);  a1 = MFMA16(Ah[1][0], Kh0, a1);
        a0 = MFMA16(Ah[0][1], Kh1, a0);  a1 = MFMA16(Ah[1][1], Kh1, a1);
        a0 = MFMA16(Am[0][0], Kh0, a0);  a1 = MFMA16(Am[1][0], Kh0, a1);
        a0 = MFMA16(Am[0][1], Kh1, a0);  a1 = MFMA16(Am[1][1], Kh1, a1);
        a0 = MFMA16(Al[0][0], Kh0, a0);  a1 = MFMA16(Al[1][0], Kh0, a1);
        a0 = MFMA16(Al[0][1], Kh1, a0);  a1 = MFMA16(Al[1][1], Kh1, a1);
        bf16x8 Km0 = *(const bf16x8*)&P.kmid[kb];
        bf16x8 Km1 = *(const bf16x8*)&P.kmid[kb + 512];
        a0 = MFMA16(Ah[0][0], Km0, a0);  a1 = MFMA16(Ah[1][0], Km0, a1);
        a0 = MFMA16(Ah[0][1], Km1, a0);  a1 = MFMA16(Ah[1][1], Km1, a1);
        a0 = MFMA16(Am[0][0], Km0, a0);  a1 = MFMA16(Am[1][0], Km0, a1);
        a0 = MFMA16(Am[0][1], Km1, a0);  a1 = MFMA16(Am[1][1], Km1, a1);
        bf16x8 Kl0 = *(const bf16x8*)&P.klo [kb];
        bf16x8 Kl1 = *(const bf16x8*)&P.klo [kb + 512];
        a0 = MFMA16(Ah[0][0], Kl0, a0);  a1 = MFMA16(Ah[1][0], Kl0, a1);
        a0 = MFMA16(Ah[0][1], Kl1, a0);  a1 = MFMA16(Ah[1][1], Kl1, a1);

        // epilogue: rows = 4 f's (q4*4+r), col j = jt*16+m16
        #pragma unroll
        for (int i01 = 0; i01 < 2; i01++) {
            floatx4 a = (i01 == 0) ? a0 : a1;
            float s = 0.f;
            s = fmaf(w2f.x, gelu_exact(a[0]), s);
            s = fmaf(w2f.y, gelu_exact(a[1]), s);
            s = fmaf(w2f.z, gelu_exact(a[2]), s);
            s = fmaf(w2f.w, gelu_exact(a[3]), s);
            s += __shfl_xor(s, 16);
            s += __shfl_xor(s, 32);
            if (lane < 16) part[i01][w][jt * 16 + lane] = s;
        }
    }
    __syncthreads();

    // ---- scores
    float score[2];
    #pragma unroll
    for (int i01 = 0; i01 < 2; i01++) {
        score[i01] = (((part[i01][0][t] + part[i01][1][t]) +
                       (part[i01][2][t] + part[i01][3][t])) + b2v) * 0.125f;
    }

    // ---- dual lockstep 256-wide bitonic sort; sorted[192] = 64th largest.
    float sv0 = score[0], sv1 = score[1];
    #pragma unroll
    for (int k = 2; k <= 256; k <<= 1) {
        #pragma unroll
        for (int j = k >> 1; j >= 1; j >>= 1) {
            float pv0, pv1;
            if (j >= 64) {
                sbuf[0][t] = sv0; sbuf[1][t] = sv1;
                __syncthreads();
                pv0 = sbuf[0][t ^ j]; pv1 = sbuf[1][t ^ j];
                __syncthreads();
            } else {
                pv0 = __shfl_xor(sv0, j);
                pv1 = __shfl_xor(sv1, j);
            }
            bool keepMin = (((t & j) == 0) == ((t & k) == 0));
            sv0 = keepMin ? fminf(sv0, pv0) : fmaxf(sv0, pv0);
            sv1 = keepMin ? fminf(sv1, pv1) : fmaxf(sv1, pv1);
        }
    }
    if (t == 192) { thr_s[0] = sv0; thr_s[1] = sv1; }
    if (t == 255) { smax_s[0] = sv0; smax_s[1] = sv1; }
    __syncthreads();

    // ---- softmax
    float p0 = (score[0] >= thr_s[0]) ? __expf(score[0] - smax_s[0]) : 0.0f;
    float p1 = (score[1] >= thr_s[1]) ? __expf(score[1] - smax_s[1]) : 0.0f;
    sc[0][t] = p0; sc[1][t] = p1;
    float ps0 = p0, ps1 = p1;
    #pragma unroll
    for (int mask = 1; mask < 64; mask <<= 1) {
        ps0 += __shfl_xor(ps0, mask);
        ps1 += __shfl_xor(ps1, mask);
    }
    if (lane == 0) { red2[0][w] = ps0; red2[1][w] = ps1; }
    __syncthreads();
    const float inv0 = 1.0f / ((red2[0][0] + red2[0][1]) + (red2[0][2] + red2[0][3]));
    const float inv1 = 1.0f / ((red2[1][0] + red2[1][1]) + (red2[1][2] + red2[1][3]));

    // ---- attn @ V
    const int d = t & 63, g = t >> 6;
    const float* vb = P.vb + bh * 256 * 64;
    float a0 = 0.f, a1 = 0.f;
    for (int j4 = 0; j4 < 16; j4++) {
        int jj = g * 64 + j4 * 4;
        float4 p40 = *(const float4*)&sc[0][jj];
        float4 p41 = *(const float4*)&sc[1][jj];
        float v0 = vb[(jj + 0) * 64 + d];
        float v1 = vb[(jj + 1) * 64 + d];
        float v2 = vb[(jj + 2) * 64 + d];
        float v3 = vb[(jj + 3) * 64 + d];
        a0 = fmaf(p40.x, v0, a0); a1 = fmaf(p41.x, v0, a1);
        a0 = fmaf(p40.y, v1, a0); a1 = fmaf(p41.y, v1, a1);
        a0 = fmaf(p40.z, v2, a0); a1 = fmaf(p41.z, v2, a1);
        a0 = fmaf(p40.w, v3, a0); a1 = fmaf(p41.w, v3, a1);
    }
    red[0][g][d] = a0; red[1][g][d] = a1;
    __syncthreads();

    if (t < 128) {
        int i01 = t >> 6, dd = t & 63;
        float o = ((red[i01][0][dd] + red[i01][1][dd]) +
                   (red[i01][2][dd] + red[i01][3][dd])) * (i01 ? inv1 : inv0);
        oarr[i01][dd] = o;
    }
    __syncthreads();

    // ---- integrated output projection: out[row, n] += sum_d o[d]*Wo[n, h*64+d]
    {
        int b = bh >> 3, h = bh & 7;
        int base0 = (b * 256 + i2 * 2) * 512;
        const float* wbase = P.Wo + h * 64;
        #pragma unroll
        for (int nn = 0; nn < 2; nn++) {
            int n = nn * 256 + t;
            const float* wrow = wbase + n * 512;
            float d0 = 0.f, d1 = 0.f;
            #pragma unroll
            for (int dd = 0; dd < 64; dd += 4) {
                float4 wv = *(const float4*)&wrow[dd];
                float4 o0 = *(const float4*)&oarr[0][dd];
                float4 o1 = *(const float4*)&oarr[1][dd];
                d0 = fmaf(wv.x, o0.x, fmaf(wv.y, o0.y, fmaf(wv.z, o0.z, fmaf(wv.w, o0.w, d0))));
                d1 = fmaf(wv.x, o1.x, fmaf(wv.y, o1.y, fmaf(wv.z, o1.z, fmaf(wv.w, o1.w, d1))));
            }
            atomicAdd(&P.out[base0 + n], d0);
            atomicAdd(&P.out[base0 + 512 + n], d1);
        }
    }
    __syncthreads();
}

// ---------------------------------------------------------------------------
__global__ __launch_bounds__(256, 4) void mega_kernel(MegaArgs P) {
    // Phase A: split inputs + init out=bo (1024 block-units)
    phase_split_init(P);
    grid_barrier(P.bar + 0);

    // Phase B: QKV projections (3072 wave-units over 4096 wave slots)
    {
        int gw = blockIdx.x * 4 + (threadIdx.x >> 6);
        if (gw < 3072) phase_mm_qkv(P, gw);
    }
    grid_barrier(P.bar + 1);

    // Phase C: fused attention + integrated out-projection (2048 units, 2/block)
    phase_fused(P, blockIdx.x);
    phase_fused(P, blockIdx.x + NBLK);
}

// ---------------------------------------------------------------------------
extern "C" void kernel_launch(void* const* d_in, const int* in_sizes, int n_in,
                              void* d_out, int out_size, void* d_ws, size_t ws_size,
                              hipStream_t stream) {
    MegaArgs A;
    A.x  = (const float*)d_in[0];
    A.Wq = (const float*)d_in[1];  A.bq = (const float*)d_in[2];
    A.Wk = (const float*)d_in[3];  A.bk = (const float*)d_in[4];
    A.Wv = (const float*)d_in[5];  A.bv = (const float*)d_in[6];
    A.w1 = (const float*)d_in[7];  A.b1 = (const float*)d_in[8];
    A.w2 = (const float*)d_in[9];  A.b2 = (const float*)d_in[10];
    A.Wo = (const float*)d_in[11]; A.bo = (const float*)d_in[12];
    A.out = (float*)d_out;

    float* qb = (float*)d_ws;
    float* vb = qb + NE;
    bf16* khi  = (bf16*)(vb + NE);
    bf16* kmid = khi + NE;
    bf16* klo  = kmid + NE;
    bf16* xs   = klo + NE;
    bf16* wqs  = xs  + 3 * NE;
    bf16* wks  = wqs + 3 * NE;
    bf16* wvs  = wks + 3 * NE;
    int*  bar  = (int*)(wvs + 3 * NE);

    A.qb = qb; A.vb = vb;
    A.khi = khi; A.kmid = kmid; A.klo = klo;
    A.xs = xs; A.wqs = wqs; A.wks = wks; A.wvs = wvs;
    A.bar = bar;

    hipMemsetAsync(bar, 0, 2 * sizeof(int), stream);
    mega_kernel<<<dim3(NBLK), dim3(256), 0, stream>>>(A);
}

// Round 14
// 182.659 us; speedup vs baseline: 4.5146x; 4.5146x over previous
//
#include <hip/hip_runtime.h>
#include <math.h>

// Problem constants: B=2, C=256, DM=512, H=8, D=64, SPARSE_K=64
typedef __bf16 bf16;
typedef __attribute__((ext_vector_type(4))) __bf16 bf16x4;
typedef __attribute__((ext_vector_type(8))) __bf16 bf16x8;
typedef __attribute__((ext_vector_type(4))) float floatx4;

// ---------------------------------------------------------------------------
// Exact gelu: 6-term Taylor erf on |t|<=0.5 (abs err <= 1.5e-8), erff fallback
// for rare outliers. (R6/R11 proven-best fused kernel uses this.)
// ---------------------------------------------------------------------------
__device__ __forceinline__ float gelu_exact(float x) {
    float tt = x * 0.70710678118654752440f;
    float e;
    if (__builtin_expect(fabsf(tt) > 0.5f, 0)) {
        e = erff(tt);
    } else {
        float s = tt * tt;
        e = tt * fmaf(s, fmaf(s, fmaf(s, fmaf(s, fmaf(s,
                -8.548327023450852e-4f, 5.223977625442188e-3f),
                -2.6866170645131252e-2f), 0.11283791670955126f),
                -0.3761263890318375f), 1.1283791670955126f);
    }
    return 0.5f * x * (1.0f + e);
}

__device__ __forceinline__ void split3(float a, bf16& h, bf16& m, bf16& l) {
    h = (bf16)a;  float r1 = a - (float)h;
    m = (bf16)r1; float r2 = r1 - (float)m;
    l = (bf16)r2;
}

// ---------------------------------------------------------------------------
// Triple-split into MFMA frag-major order for [512][512] matrices; 5 matrices
// batched via blockIdx.z. (row,k) -> ((rt*16+ks)*64 + q4*16 + rm)*8 + u.
// ---------------------------------------------------------------------------
struct SplitArgs {
    const float* src[5];
    bf16* h[5]; bf16* m[5]; bf16* l[5];
};

__global__ __launch_bounds__(256) void split3_512_kernel(SplitArgs S) {
    int z = blockIdx.z;
    const float* src = S.src[z];
    bf16* dh = S.h[z]; bf16* dm = S.m[z]; bf16* dl = S.l[z];
    int t = blockIdx.x * 256 + threadIdx.x;
    int row = t >> 7, kq = (t & 127) * 4;
    int rt = row >> 4, rm = row & 15;
    int ks = kq >> 5, q4 = (kq >> 3) & 3, u0 = kq & 7;
    int dst = ((rt * 16 + ks) * 64 + q4 * 16 + rm) * 8 + u0;
    float4 vv = *(const float4*)&src[row * 512 + kq];
    float a4[4] = {vv.x, vv.y, vv.z, vv.w};
    bf16x4 h, m, l;
    #pragma unroll
    for (int u = 0; u < 4; u++) {
        bf16 hh, mm, ll;
        split3(a4[u], hh, mm, ll);
        h[u] = hh; m[u] = mm; l[u] = ll;
    }
    *(bf16x4*)&dh[dst] = h;
    *(bf16x4*)&dm[dst] = m;
    *(bf16x4*)&dl[dst] = l;
}

// ---------------------------------------------------------------------------
// C = A @ W^T + bias via triple-split bf16 MFMA. One wave per block computing
// a 16(m) x 16(n) tile; grid (32 nx, 32 ny, nz) — 12 blocks/CU for QKV
// (R11-validated: 4x more blocks than 16x64 tiles won ~30 us of tail).
// mode 0: fp32 [m*512+n]; mode 1: heads fp32 (b,h,c,d);
// mode 2: K written directly as frag-major split triple.
// ---------------------------------------------------------------------------
struct MM2Args {
    const bf16 *Ah, *Am, *Al;
    const bf16 *Wh[3], *Wm[3], *Wl[3];
    const float* bias[3];
    float* outf[3];
    bf16 *kh, *km, *kl;
    int mode[3];
};

__global__ __launch_bounds__(64) void mm_mfma_kernel(MM2Args A) {
    const int z = blockIdx.z;
    const bf16* Wh = A.Wh[z]; const bf16* Wm = A.Wm[z]; const bf16* Wl = A.Wl[z];
    const float* bias = A.bias[z];
    const int lane = threadIdx.x;
    const int m16 = lane & 15, q4 = lane >> 4;
    const int mt = blockIdx.y, bx = blockIdx.x;

    floatx4 acc;
    {
        float bv = bias[bx * 16 + m16];
        acc[0] = bv; acc[1] = bv; acc[2] = bv; acc[3] = bv;
    }

    #pragma unroll 4
    for (int ks = 0; ks < 16; ks++) {
        int sa = ((mt * 16 + ks) * 64 + lane) * 8;
        bf16x8 ah = *(const bf16x8*)&A.Ah[sa];
        bf16x8 am = *(const bf16x8*)&A.Am[sa];
        bf16x8 al = *(const bf16x8*)&A.Al[sa];
        int sw = ((bx * 16 + ks) * 64 + lane) * 8;
        bf16x8 wh = *(const bf16x8*)&Wh[sw];
        bf16x8 wm = *(const bf16x8*)&Wm[sw];
        bf16x8 wl = *(const bf16x8*)&Wl[sw];
        acc = __builtin_amdgcn_mfma_f32_16x16x32_bf16(ah, wh, acc, 0, 0, 0);
        acc = __builtin_amdgcn_mfma_f32_16x16x32_bf16(ah, wm, acc, 0, 0, 0);
        acc = __builtin_amdgcn_mfma_f32_16x16x32_bf16(am, wh, acc, 0, 0, 0);
        acc = __builtin_amdgcn_mfma_f32_16x16x32_bf16(ah, wl, acc, 0, 0, 0);
        acc = __builtin_amdgcn_mfma_f32_16x16x32_bf16(al, wh, acc, 0, 0, 0);
        acc = __builtin_amdgcn_mfma_f32_16x16x32_bf16(am, wm, acc, 0, 0, 0);
    }

    const int mode = A.mode[z];
    const int n = bx * 16 + m16;
    #pragma unroll
    for (int r = 0; r < 4; r++) {
        int m = mt * 16 + q4 * 4 + r;
        float val = acc[r];
        if (mode == 0) {
            A.outf[z][m * 512 + n] = val;
        } else if (mode == 1) {
            A.outf[z][(((m >> 8) * 8 + (n >> 6)) * 256 + (m & 255)) * 64 + (n & 63)] = val;
        } else {
            int krow = ((m >> 8) * 8 + (n >> 6)) * 256 + (m & 255);
            int d = n & 63;
            int dst = (((krow >> 4) * 2 + (d >> 5)) * 64 + ((d >> 3) & 3) * 16 + (krow & 15)) * 8 + (d & 7);
            bf16 h, mm, l;
            split3(val, h, mm, l);
            A.kh[dst] = h; A.km[dst] = mm; A.kl[dst] = l;
        }
    }
}

// ---------------------------------------------------------------------------
// Fused per-(bh, i-pair) — proven-best version (R6/R11, ~89 us):
// res^T[f,j] = qpb_i[f] + sum_e A_i[f,e]*K[j,e], A_i in registers per wave,
// NI=2 (K frags shared across 2 queries), single 12-MFMA chain, erff-gelu,
// dual bitonic top-64, softmax, attn@V, split-triple output.
// ---------------------------------------------------------------------------
__global__ __launch_bounds__(256, 3) void fused_mfma_attn_kernel(
    const float* __restrict__ q, const float* __restrict__ v,
    const bf16* __restrict__ khi, const bf16* __restrict__ kmid, const bf16* __restrict__ klo,
    const float* __restrict__ w1, const float* __restrict__ b1,
    const float* __restrict__ w2, const float* __restrict__ b2,
    bf16* __restrict__ oh, bf16* __restrict__ om, bf16* __restrict__ ol)
{
    const int i2 = blockIdx.x;     // query pair: i = 2*i2 + i01
    const int bh = blockIdx.y;
    const int t  = threadIdx.x;
    const int lane = t & 63, w = t >> 6;
    const int m16 = lane & 15, q4 = lane >> 4;

    __shared__ float part[2][4][256];   // per-wave f-partials of scores
    __shared__ float sc[2][256];        // softmax probabilities
    __shared__ float qpb_s[2][64];
    __shared__ float sbuf[2][256];      // bitonic cross-wave exchange
    __shared__ float red[2][4][64];
    __shared__ float red2[2][4];
    __shared__ float thr_s[2], smax_s[2];

    const int f = w * 16 + m16;         // this lane's f (A-operand M index)
    const float* w1row = w1 + f * 192;

    // ---- build A_i fragments in registers + qpb
    bf16x8 Ah[2][2], Am[2][2], Al[2][2];
    #pragma unroll
    for (int i01 = 0; i01 < 2; i01++) {
        const float* qrow = q + (bh * 256 + i2 * 2 + i01) * 64;
        float qa = 0.f;
        #pragma unroll
        for (int ks = 0; ks < 2; ks++) {
            int e0 = ks * 32 + q4 * 8;
            #pragma unroll
            for (int u = 0; u < 2; u++) {
                int e = e0 + u * 4;
                float4 wa = *(const float4*)&w1row[e];
                float4 wb = *(const float4*)&w1row[64 + e];
                float4 wc = *(const float4*)&w1row[128 + e];
                float4 qv = *(const float4*)&qrow[e];
                qa += wa.x * qv.x + wa.y * qv.y + wa.z * qv.z + wa.w * qv.w;
                float av[4];
                av[0] = fmaf(wc.x, qv.x, wb.x);
                av[1] = fmaf(wc.y, qv.y, wb.y);
                av[2] = fmaf(wc.z, qv.z, wb.z);
                av[3] = fmaf(wc.w, qv.w, wb.w);
                #pragma unroll
                for (int uu = 0; uu < 4; uu++) {
                    bf16 h, m, l;
                    split3(av[uu], h, m, l);
                    Ah[i01][ks][u * 4 + uu] = h;
                    Am[i01][ks][u * 4 + uu] = m;
                    Al[i01][ks][u * 4 + uu] = l;
                }
            }
        }
        qa += __shfl_xor(qa, 16);
        qa += __shfl_xor(qa, 32);
        if (lane < 16) qpb_s[i01][w * 16 + lane] = qa + b1[w * 16 + lane];
    }
    __syncthreads();

    floatx4 qpbr[2];
    qpbr[0] = *(const floatx4*)&qpb_s[0][w * 16 + q4 * 4];
    qpbr[1] = *(const floatx4*)&qpb_s[1][w * 16 + q4 * 4];
    const float4 w2f = *(const float4*)&w2[w * 16 + q4 * 4];
    const float b2v = b2[0];

    // ---- main loop over j-tiles: MFMA + immediate epilogue (no barriers)
    #pragma unroll 2
    for (int jt = 0; jt < 16; jt++) {
        int base = ((bh * 16 + jt) * 2 * 64 + lane) * 8;
        bf16x8 Kh0 = *(const bf16x8*)&khi [base];
        bf16x8 Km0 = *(const bf16x8*)&kmid[base];
        bf16x8 Kl0 = *(const bf16x8*)&klo [base];
        bf16x8 Kh1 = *(const bf16x8*)&khi [base + 512];
        bf16x8 Km1 = *(const bf16x8*)&kmid[base + 512];
        bf16x8 Kl1 = *(const bf16x8*)&klo [base + 512];
        #pragma unroll
        for (int i01 = 0; i01 < 2; i01++) {
            floatx4 a = qpbr[i01];
            a = __builtin_amdgcn_mfma_f32_16x16x32_bf16(Ah[i01][0], Kh0, a, 0, 0, 0);
            a = __builtin_amdgcn_mfma_f32_16x16x32_bf16(Ah[i01][0], Km0, a, 0, 0, 0);
            a = __builtin_amdgcn_mfma_f32_16x16x32_bf16(Am[i01][0], Kh0, a, 0, 0, 0);
            a = __builtin_amdgcn_mfma_f32_16x16x32_bf16(Ah[i01][0], Kl0, a, 0, 0, 0);
            a = __builtin_amdgcn_mfma_f32_16x16x32_bf16(Al[i01][0], Kh0, a, 0, 0, 0);
            a = __builtin_amdgcn_mfma_f32_16x16x32_bf16(Am[i01][0], Km0, a, 0, 0, 0);
            a = __builtin_amdgcn_mfma_f32_16x16x32_bf16(Ah[i01][1], Kh1, a, 0, 0, 0);
            a = __builtin_amdgcn_mfma_f32_16x16x32_bf16(Ah[i01][1], Km1, a, 0, 0, 0);
            a = __builtin_amdgcn_mfma_f32_16x16x32_bf16(Am[i01][1], Kh1, a, 0, 0, 0);
            a = __builtin_amdgcn_mfma_f32_16x16x32_bf16(Ah[i01][1], Kl1, a, 0, 0, 0);
            a = __builtin_amdgcn_mfma_f32_16x16x32_bf16(Al[i01][1], Kh1, a, 0, 0, 0);
            a = __builtin_amdgcn_mfma_f32_16x16x32_bf16(Am[i01][1], Km1, a, 0, 0, 0);
            // epilogue: rows of a = 4 f's (q4*4+r), col = j = jt*16+m16
            float s = 0.f;
            s = fmaf(w2f.x, gelu_exact(a[0]), s);
            s = fmaf(w2f.y, gelu_exact(a[1]), s);
            s = fmaf(w2f.z, gelu_exact(a[2]), s);
            s = fmaf(w2f.w, gelu_exact(a[3]), s);
            s += __shfl_xor(s, 16);
            s += __shfl_xor(s, 32);
            if (lane < 16) part[i01][w][jt * 16 + lane] = s;
        }
    }
    __syncthreads();

    // ---- scores
    float score[2];
    #pragma unroll
    for (int i01 = 0; i01 < 2; i01++) {
        score[i01] = (((part[i01][0][t] + part[i01][1][t]) +
                       (part[i01][2][t] + part[i01][3][t])) + b2v) * 0.125f;
    }

    // ---- dual lockstep 256-wide bitonic sort; sorted[192] = 64th largest.
    float sv0 = score[0], sv1 = score[1];
    #pragma unroll
    for (int k = 2; k <= 256; k <<= 1) {
        #pragma unroll
        for (int j = k >> 1; j >= 1; j >>= 1) {
            float pv0, pv1;
            if (j >= 64) {
                sbuf[0][t] = sv0; sbuf[1][t] = sv1;
                __syncthreads();
                pv0 = sbuf[0][t ^ j]; pv1 = sbuf[1][t ^ j];
                __syncthreads();
            } else {
                pv0 = __shfl_xor(sv0, j);
                pv1 = __shfl_xor(sv1, j);
            }
            bool keepMin = (((t & j) == 0) == ((t & k) == 0));
            sv0 = keepMin ? fminf(sv0, pv0) : fmaxf(sv0, pv0);
            sv1 = keepMin ? fminf(sv1, pv1) : fmaxf(sv1, pv1);
        }
    }
    if (t == 192) { thr_s[0] = sv0; thr_s[1] = sv1; }
    if (t == 255) { smax_s[0] = sv0; smax_s[1] = sv1; }
    __syncthreads();

    // ---- softmax numerator + denominator
    float p0 = (score[0] >= thr_s[0]) ? __expf(score[0] - smax_s[0]) : 0.0f;
    float p1 = (score[1] >= thr_s[1]) ? __expf(score[1] - smax_s[1]) : 0.0f;
    sc[0][t] = p0; sc[1][t] = p1;
    float ps0 = p0, ps1 = p1;
    #pragma unroll
    for (int mask = 1; mask < 64; mask <<= 1) {
        ps0 += __shfl_xor(ps0, mask);
        ps1 += __shfl_xor(ps1, mask);
    }
    if (lane == 0) { red2[0][w] = ps0; red2[1][w] = ps1; }
    __syncthreads();
    const float inv0 = 1.0f / ((red2[0][0] + red2[0][1]) + (red2[0][2] + red2[0][3]));
    const float inv1 = 1.0f / ((red2[1][0] + red2[1][1]) + (red2[1][2] + red2[1][3]));

    // ---- attn @ V (v loads shared between the two i's)
    const int d = t & 63, g = t >> 6;
    const float* vb = v + bh * 256 * 64;
    float a0 = 0.f, a1 = 0.f;
    for (int j4 = 0; j4 < 16; j4++) {
        int jj = g * 64 + j4 * 4;
        float4 p40 = *(const float4*)&sc[0][jj];
        float4 p41 = *(const float4*)&sc[1][jj];
        float v0 = vb[(jj + 0) * 64 + d];
        float v1 = vb[(jj + 1) * 64 + d];
        float v2 = vb[(jj + 2) * 64 + d];
        float v3 = vb[(jj + 3) * 64 + d];
        a0 = fmaf(p40.x, v0, a0); a1 = fmaf(p41.x, v0, a1);
        a0 = fmaf(p40.y, v1, a0); a1 = fmaf(p41.y, v1, a1);
        a0 = fmaf(p40.z, v2, a0); a1 = fmaf(p41.z, v2, a1);
        a0 = fmaf(p40.w, v3, a0); a1 = fmaf(p41.w, v3, a1);
    }
    red[0][g][d] = a0; red[1][g][d] = a1;
    __syncthreads();

    // ---- output: (B,H,C,D)->(B,C,DM) row, written as split frag-major triple
    if (t < 128) {
        int i01 = t >> 6, dd = t & 63;
        float o = ((red[i01][0][dd] + red[i01][1][dd]) +
                   (red[i01][2][dd] + red[i01][3][dd])) * (i01 ? inv1 : inv0);
        int b = bh >> 3, h = bh & 7;
        int row = b * 256 + i2 * 2 + i01;
        int n = h * 64 + dd;
        int dst = (((row >> 4) * 16 + (n >> 5)) * 64 + ((n >> 3) & 3) * 16 + (row & 15)) * 8 + (n & 7);
        bf16 hh, mm, ll;
        split3(o, hh, mm, ll);
        oh[dst] = hh; om[dst] = mm; ol[dst] = ll;
    }
}

// ---------------------------------------------------------------------------
extern "C" void kernel_launch(void* const* d_in, const int* in_sizes, int n_in,
                              void* d_out, int out_size, void* d_ws, size_t ws_size,
                              hipStream_t stream) {
    const float* x  = (const float*)d_in[0];
    const float* Wq = (const float*)d_in[1];
    const float* bq = (const float*)d_in[2];
    const float* Wk = (const float*)d_in[3];
    const float* bk = (const float*)d_in[4];
    const float* Wv = (const float*)d_in[5];
    const float* bv = (const float*)d_in[6];
    const float* w1 = (const float*)d_in[7];
    const float* b1 = (const float*)d_in[8];
    const float* w2 = (const float*)d_in[9];
    const float* b2 = (const float*)d_in[10];
    const float* Wo = (const float*)d_in[11];
    const float* bo = (const float*)d_in[12];
    float* out = (float*)d_out;

    const int NE = 262144;   // 512*512
    float* qb  = (float*)d_ws;          // q (b,h,c,d) fp32
    float* vb  = qb + NE;               // v (b,h,c,d) fp32
    bf16* base = (bf16*)(vb + NE);
    bf16* khi  = base;            bf16* kmid = khi + NE;    bf16* klo = kmid + NE;
    bf16* xs   = klo + NE;        // hi/mid/lo triples follow
    bf16* wqs  = xs  + 3 * NE;
    bf16* wks  = wqs + 3 * NE;
    bf16* wvs  = wks + 3 * NE;
    bf16* wos  = wvs + 3 * NE;
    bf16* oas  = wos + 3 * NE;

    // 1) split x, Wq, Wk, Wv, Wo into frag-major bf16 triples
    {
        SplitArgs S;
        const float* srcs[5] = {x, Wq, Wk, Wv, Wo};
        bf16* dsts[5] = {xs, wqs, wks, wvs, wos};
        for (int z = 0; z < 5; z++) {
            S.src[z] = srcs[z];
            S.h[z] = dsts[z]; S.m[z] = dsts[z] + NE; S.l[z] = dsts[z] + 2 * NE;
        }
        split3_512_kernel<<<dim3(256, 1, 5), 256, 0, stream>>>(S);
    }
    // 2) QKV projections; K written directly as split frag-major triple
    {
        MM2Args M;
        M.Ah = xs; M.Am = xs + NE; M.Al = xs + 2 * NE;
        M.Wh[0] = wqs; M.Wm[0] = wqs + NE; M.Wl[0] = wqs + 2 * NE;
        M.Wh[1] = wks; M.Wm[1] = wks + NE; M.Wl[1] = wks + 2 * NE;
        M.Wh[2] = wvs; M.Wm[2] = wvs + NE; M.Wl[2] = wvs + 2 * NE;
        M.bias[0] = bq; M.bias[1] = bk; M.bias[2] = bv;
        M.outf[0] = qb; M.outf[1] = nullptr; M.outf[2] = vb;
        M.kh = khi; M.km = kmid; M.kl = klo;
        M.mode[0] = 1; M.mode[1] = 2; M.mode[2] = 1;
        mm_mfma_kernel<<<dim3(32, 32, 3), 64, 0, stream>>>(M);
    }
    // 3) fused second-order scores + top-64 + softmax + attn@V (+ split out)
    fused_mfma_attn_kernel<<<dim3(128, 16), 256, 0, stream>>>(
        qb, vb, khi, kmid, klo, w1, b1, w2, b2,
        oas, oas + NE, oas + 2 * NE);
    // 4) output projection
    {
        MM2Args M;
        M.Ah = oas; M.Am = oas + NE; M.Al = oas + 2 * NE;
        M.Wh[0] = wos; M.Wm[0] = wos + NE; M.Wl[0] = wos + 2 * NE;
        M.Wh[1] = wos; M.Wm[1] = wos; M.Wl[1] = wos;
        M.Wh[2] = wos; M.Wm[2] = wos; M.Wl[2] = wos;
        M.bias[0] = bo; M.bias[1] = bo; M.bias[2] = bo;
        M.outf[0] = out; M.outf[1] = out; M.outf[2] = out;
        M.kh = khi; M.km = kmid; M.kl = klo;
        M.mode[0] = 0; M.mode[1] = 0; M.mode[2] = 0;
        mm_mfma_kernel<<<dim3(32, 32, 1), 64, 0, stream>>>(M);
    }
}